// Round 1
// baseline (1147.809 us; speedup 1.0000x reference)
//
#include <hip/hip_runtime.h>

#define N_NODES 10000
#define N_EDGES 640000
#define FEATS 128

// ---------------------------------------------------------------------------
// Kernel 1: h = x  (init aggregation buffer with self term, since h = x + agg)
// ---------------------------------------------------------------------------
__global__ void copy_x_kernel(const float* __restrict__ x, float* __restrict__ h) {
    int i = blockIdx.x * blockDim.x + threadIdx.x;
    if (i < N_NODES * FEATS / 4) {
        reinterpret_cast<float4*>(h)[i] = reinterpret_cast<const float4*>(x)[i];
    }
}

// ---------------------------------------------------------------------------
// Kernel 2: transpose W [o][k] -> Wt [k][o]  (once, tiny: 16K elements)
// ---------------------------------------------------------------------------
__global__ void transpose_w_kernel(const float* __restrict__ W, float* __restrict__ Wt) {
    int i = blockIdx.x * blockDim.x + threadIdx.x;
    if (i < FEATS * FEATS) {
        int o = i >> 7;      // W row
        int k = i & 127;     // W col
        Wt[k * FEATS + o] = W[i];
    }
}

// ---------------------------------------------------------------------------
// Kernel 3: edge scatter  h[dst] += x[src]
// 32 threads per edge, each thread: float4 gather + 4 scalar f32 atomics.
// ---------------------------------------------------------------------------
__global__ void scatter_kernel(const float* __restrict__ x,
                               const int* __restrict__ src,
                               const int* __restrict__ dst,
                               float* __restrict__ h) {
    int gid = blockIdx.x * blockDim.x + threadIdx.x;   // [0, N_EDGES*32)
    if (gid >= N_EDGES * 32) return;
    int e = gid >> 5;           // edge id
    int f = (gid & 31) << 2;    // feature offset (0,4,...,124)
    int s = src[e];
    int d = dst[e];
    float4 v = *reinterpret_cast<const float4*>(x + s * FEATS + f);
    float* o = h + d * FEATS + f;
    atomicAdd(o + 0, v.x);
    atomicAdd(o + 1, v.y);
    atomicAdd(o + 2, v.z);
    atomicAdd(o + 3, v.w);
}

// ---------------------------------------------------------------------------
// Kernel 4: out = h @ W^T + b
// Block: 256 threads, 32 rows of h. Wt staged in LDS (64 KB), conflict-free.
// Thread (tx=tid&31, ty=tid>>5): rows row0..row0+3 (row0=blk*32+4*ty),
// cols 4*tx..4*tx+3. k-loop unrolled by 4 with float4 LDS reads.
// ---------------------------------------------------------------------------
__global__ __launch_bounds__(256) void gemm_kernel(const float* __restrict__ h,
                                                   const float* __restrict__ Wt,
                                                   const float* __restrict__ b,
                                                   float* __restrict__ out) {
    __shared__ float sWt[FEATS * FEATS];   // sWt[k*128 + o], 64 KB
    int tid = threadIdx.x;

    // Stage Wt: fully coalesced float4 copy, conflict-free LDS writes.
    const float4* Wt4 = reinterpret_cast<const float4*>(Wt);
    float4* sWt4 = reinterpret_cast<float4*>(sWt);
    #pragma unroll
    for (int i = 0; i < FEATS * FEATS / 4 / 256; ++i) {
        int idx = tid + i * 256;
        sWt4[idx] = Wt4[idx];
    }
    __syncthreads();

    int tx = tid & 31;     // col group: cols 4*tx .. 4*tx+3
    int ty = tid >> 5;     // row group
    int row0 = blockIdx.x * 32 + ty * 4;

    float acc[4][4] = {};

    // Clamp rows so global loads never go OOB (only last block affected).
    int rowc[4];
    #pragma unroll
    for (int r = 0; r < 4; ++r) {
        int row = row0 + r;
        rowc[r] = row < N_NODES ? row : N_NODES - 1;
    }

    for (int k = 0; k < FEATS; k += 4) {
        // W fragment: 4 k-slices, each a float4 of 4 consecutive cols.
        float4 w4[4];
        #pragma unroll
        for (int j = 0; j < 4; ++j) {
            // float4 index: row (k+j) has 32 float4s; lanes tx cover all banks.
            w4[j] = sWt4[(k + j) * (FEATS / 4) + tx];
        }
        #pragma unroll
        for (int r = 0; r < 4; ++r) {
            float4 h4 = *reinterpret_cast<const float4*>(h + rowc[r] * FEATS + k);
            float hk[4] = {h4.x, h4.y, h4.z, h4.w};
            #pragma unroll
            for (int j = 0; j < 4; ++j) {
                acc[r][0] += hk[j] * w4[j].x;
                acc[r][1] += hk[j] * w4[j].y;
                acc[r][2] += hk[j] * w4[j].z;
                acc[r][3] += hk[j] * w4[j].w;
            }
        }
    }

    float4 bias = reinterpret_cast<const float4*>(b)[tx];
    #pragma unroll
    for (int r = 0; r < 4; ++r) {
        int row = row0 + r;
        if (row < N_NODES) {
            float4 o;
            o.x = acc[r][0] + bias.x;
            o.y = acc[r][1] + bias.y;
            o.z = acc[r][2] + bias.z;
            o.w = acc[r][3] + bias.w;
            reinterpret_cast<float4*>(out + row * FEATS)[tx] = o;
        }
    }
}

// ---------------------------------------------------------------------------
extern "C" void kernel_launch(void* const* d_in, const int* in_sizes, int n_in,
                              void* d_out, int out_size, void* d_ws, size_t ws_size,
                              hipStream_t stream) {
    const float* x   = (const float*)d_in[0];
    const int*   src = (const int*)d_in[1];
    const int*   dst = (const int*)d_in[2];
    const float* W   = (const float*)d_in[3];
    const float* b   = (const float*)d_in[4];
    float* out = (float*)d_out;

    // Workspace layout: h [N_NODES*FEATS fp32] | Wt [128*128 fp32]
    float* h  = (float*)d_ws;
    float* Wt = h + N_NODES * FEATS;

    // 1. h = x
    copy_x_kernel<<<(N_NODES * FEATS / 4 + 255) / 256, 256, 0, stream>>>(x, h);
    // 2. Wt = W^T (independent of 1, same stream serializes, cost ~1us)
    transpose_w_kernel<<<(FEATS * FEATS + 255) / 256, 256, 0, stream>>>(W, Wt);
    // 3. h[dst] += x[src]
    scatter_kernel<<<(N_EDGES * 32 + 255) / 256, 256, 0, stream>>>(x, src, dst, h);
    // 4. out = h @ W^T + b
    gemm_kernel<<<(N_NODES + 31) / 32, 256, 0, stream>>>(h, Wt, b, out);
}

// Round 2
// 204.180 us; speedup vs baseline: 5.6216x; 5.6216x over previous
//
#include <hip/hip_runtime.h>

#define N_NODES 10000
#define N_EDGES 640000
#define FEATS 128

// ---------------------------------------------------------------------------
// CSR build kernel 1: deg[dst[e]]++  (int atomics, 10K counters, low contention)
// ---------------------------------------------------------------------------
__global__ void hist_kernel(const int* __restrict__ dst, int* __restrict__ deg) {
    int e = blockIdx.x * blockDim.x + threadIdx.x;
    if (e < N_EDGES) atomicAdd(&deg[dst[e]], 1);
}

// ---------------------------------------------------------------------------
// CSR build kernel 2: exclusive scan of deg -> off[0..N_NODES], cursor = off
// Single block, 1024 threads, 10 elements/thread (covers 10240 >= 10001).
// ---------------------------------------------------------------------------
__global__ __launch_bounds__(1024) void scan_kernel(const int* __restrict__ deg,
                                                    int* __restrict__ off,
                                                    int* __restrict__ cursor) {
    __shared__ int sums[1024];
    const int CH = 10;
    int tid = threadIdx.x;
    int base = tid * CH;
    int local[CH];
    int s = 0;
    #pragma unroll
    for (int i = 0; i < CH; ++i) {
        int idx = base + i;
        int v = (idx < N_NODES) ? deg[idx] : 0;
        local[i] = s;
        s += v;
    }
    sums[tid] = s;
    __syncthreads();
    // Hillis-Steele inclusive scan over 1024 per-thread sums
    for (int d = 1; d < 1024; d <<= 1) {
        int v = 0;
        if (tid >= d) v = sums[tid - d];
        __syncthreads();
        if (tid >= d) sums[tid] += v;
        __syncthreads();
    }
    int prefix = (tid > 0) ? sums[tid - 1] : 0;
    #pragma unroll
    for (int i = 0; i < CH; ++i) {
        int idx = base + i;
        if (idx <= N_NODES) {
            int val = prefix + local[i];
            off[idx] = val;
            if (idx < N_NODES) cursor[idx] = val;
        }
    }
}

// ---------------------------------------------------------------------------
// CSR build kernel 3: bucket edges by dst: esrc[off[d] + pos] = src[e]
// ---------------------------------------------------------------------------
__global__ void bucket_kernel(const int* __restrict__ src,
                              const int* __restrict__ dst,
                              int* __restrict__ cursor,
                              int* __restrict__ esrc) {
    int e = blockIdx.x * blockDim.x + threadIdx.x;
    if (e < N_EDGES) {
        int d = dst[e];
        int pos = atomicAdd(&cursor[d], 1);
        esrc[pos] = src[e];
    }
}

// ---------------------------------------------------------------------------
// Gather kernel: h[n] = x[n] + sum_{e in in-edges(n)} x[esrc[e]]
// One block (256 threads) per node. tx = feature float4 group (32 lanes),
// ty = 8-way edge parallelism. LDS reduce across ty at the end.
// x rows are 512 B contiguous -> fully coalesced; x is L2/L3 resident.
// ---------------------------------------------------------------------------
__global__ __launch_bounds__(256) void gather_kernel(const float* __restrict__ x,
                                                     const int* __restrict__ esrc,
                                                     const int* __restrict__ off,
                                                     float* __restrict__ h) {
    int node = blockIdx.x;
    int tid = threadIdx.x;
    int tx = tid & 31;
    int ty = tid >> 5;
    int start = off[node];
    int end = off[node + 1];

    float4 acc = make_float4(0.f, 0.f, 0.f, 0.f);
    for (int e = start + ty; e < end; e += 8) {
        int s = esrc[e];
        float4 v = *reinterpret_cast<const float4*>(x + s * FEATS + tx * 4);
        acc.x += v.x; acc.y += v.y; acc.z += v.z; acc.w += v.w;
    }

    __shared__ float4 red[8][32];
    red[ty][tx] = acc;
    __syncthreads();

    if (ty == 0) {
        float4 t = red[0][tx];
        #pragma unroll
        for (int r = 1; r < 8; ++r) {
            float4 u = red[r][tx];
            t.x += u.x; t.y += u.y; t.z += u.z; t.w += u.w;
        }
        float4 xs = *reinterpret_cast<const float4*>(x + node * FEATS + tx * 4);
        t.x += xs.x; t.y += xs.y; t.z += xs.z; t.w += xs.w;
        *reinterpret_cast<float4*>(h + node * FEATS + tx * 4) = t;
    }
}

// ---------------------------------------------------------------------------
// Transpose W [o][k] -> Wt [k][o]  (tiny, once)
// ---------------------------------------------------------------------------
__global__ void transpose_w_kernel(const float* __restrict__ W, float* __restrict__ Wt) {
    int i = blockIdx.x * blockDim.x + threadIdx.x;
    if (i < FEATS * FEATS) {
        int o = i >> 7;
        int k = i & 127;
        Wt[k * FEATS + o] = W[i];
    }
}

// ---------------------------------------------------------------------------
// GEMM: out = h @ W^T + b.  256 threads / 32 rows per block, Wt in LDS.
// ---------------------------------------------------------------------------
__global__ __launch_bounds__(256) void gemm_kernel(const float* __restrict__ h,
                                                   const float* __restrict__ Wt,
                                                   const float* __restrict__ b,
                                                   float* __restrict__ out) {
    __shared__ float sWt[FEATS * FEATS];   // sWt[k*128 + o], 64 KB
    int tid = threadIdx.x;

    const float4* Wt4 = reinterpret_cast<const float4*>(Wt);
    float4* sWt4 = reinterpret_cast<float4*>(sWt);
    #pragma unroll
    for (int i = 0; i < FEATS * FEATS / 4 / 256; ++i) {
        int idx = tid + i * 256;
        sWt4[idx] = Wt4[idx];
    }
    __syncthreads();

    int tx = tid & 31;
    int ty = tid >> 5;
    int row0 = blockIdx.x * 32 + ty * 4;

    float acc[4][4] = {};

    int rowc[4];
    #pragma unroll
    for (int r = 0; r < 4; ++r) {
        int row = row0 + r;
        rowc[r] = row < N_NODES ? row : N_NODES - 1;
    }

    for (int k = 0; k < FEATS; k += 4) {
        float4 w4[4];
        #pragma unroll
        for (int j = 0; j < 4; ++j) {
            w4[j] = sWt4[(k + j) * (FEATS / 4) + tx];
        }
        #pragma unroll
        for (int r = 0; r < 4; ++r) {
            float4 h4 = *reinterpret_cast<const float4*>(h + rowc[r] * FEATS + k);
            float hk[4] = {h4.x, h4.y, h4.z, h4.w};
            #pragma unroll
            for (int j = 0; j < 4; ++j) {
                acc[r][0] += hk[j] * w4[j].x;
                acc[r][1] += hk[j] * w4[j].y;
                acc[r][2] += hk[j] * w4[j].z;
                acc[r][3] += hk[j] * w4[j].w;
            }
        }
    }

    float4 bias = reinterpret_cast<const float4*>(b)[tx];
    #pragma unroll
    for (int r = 0; r < 4; ++r) {
        int row = row0 + r;
        if (row < N_NODES) {
            float4 o;
            o.x = acc[r][0] + bias.x;
            o.y = acc[r][1] + bias.y;
            o.z = acc[r][2] + bias.z;
            o.w = acc[r][3] + bias.w;
            reinterpret_cast<float4*>(out + row * FEATS)[tx] = o;
        }
    }
}

// ---------------------------------------------------------------------------
extern "C" void kernel_launch(void* const* d_in, const int* in_sizes, int n_in,
                              void* d_out, int out_size, void* d_ws, size_t ws_size,
                              hipStream_t stream) {
    const float* x   = (const float*)d_in[0];
    const int*   src = (const int*)d_in[1];
    const int*   dst = (const int*)d_in[2];
    const float* W   = (const float*)d_in[3];
    const float* b   = (const float*)d_in[4];
    float* out = (float*)d_out;

    // Workspace layout (floats/ints are both 4 B):
    //   h      : N_NODES*FEATS f32      (5.12 MB)
    //   Wt     : FEATS*FEATS f32        (64 KB)
    //   deg    : N_NODES int            (40 KB)
    //   off    : N_NODES+1 int          (40 KB)
    //   cursor : N_NODES int            (40 KB)
    //   esrc   : N_EDGES int            (2.56 MB)
    float* h   = (float*)d_ws;
    float* Wt  = h + N_NODES * FEATS;
    int* deg    = (int*)(Wt + FEATS * FEATS);
    int* off    = deg + N_NODES;
    int* cursor = off + N_NODES + 1;
    int* esrc   = cursor + N_NODES;

    hipMemsetAsync(deg, 0, N_NODES * sizeof(int), stream);

    hist_kernel<<<(N_EDGES + 255) / 256, 256, 0, stream>>>(dst, deg);
    scan_kernel<<<1, 1024, 0, stream>>>(deg, off, cursor);
    bucket_kernel<<<(N_EDGES + 255) / 256, 256, 0, stream>>>(src, dst, cursor, esrc);
    gather_kernel<<<N_NODES, 256, 0, stream>>>(x, esrc, off, h);
    transpose_w_kernel<<<(FEATS * FEATS + 255) / 256, 256, 0, stream>>>(W, Wt);
    gemm_kernel<<<(N_NODES + 31) / 32, 256, 0, stream>>>(h, Wt, b, out);
}